// Round 18
// baseline (78.938 us; speedup 1.0000x reference)
//
#include <hip/hip_runtime.h>
#include <hip/hip_bf16.h>

#define N_ 16
#define L_ 256
#define C_ 512
#define HW_ 1024
#define HEADS_ 16
#define DH_ 32

typedef unsigned short u16;
typedef unsigned int u32;
typedef __attribute__((ext_vector_type(8))) short short8_t;
typedef __attribute__((ext_vector_type(4))) float f32x4;

__device__ __forceinline__ u16 f2bs(float f) {
    union { float f; u32 i; } x; x.f = f;
    u32 r = x.i + 0x7fffu + ((x.i >> 16) & 1u);
    return (u16)(r >> 16);
}
__device__ __forceinline__ u32 cvt_pk_bf16(float lo, float hi) {
    u32 r;
    asm("v_cvt_pk_bf16_f32 %0, %1, %2" : "=v"(r) : "v"(lo), "v"(hi));
    return r;
}
__device__ __forceinline__ void cvt8(const float* __restrict__ src, void* dst) {
    float4 lo = *(const float4*)src;
    float4 hi = *(const float4*)(src + 4);
    union { u32 w[4]; short8_t v; } pk;
    pk.w[0] = cvt_pk_bf16(lo.x, lo.y);
    pk.w[1] = cvt_pk_bf16(lo.z, lo.w);
    pk.w[2] = cvt_pk_bf16(hi.x, hi.y);
    pk.w[3] = cvt_pk_bf16(hi.z, hi.w);
    *(short8_t*)dst = pk.v;
}
#define AS1(p) (const __attribute__((address_space(1))) void*)(p)
#define AS3(p) (__attribute__((address_space(3))) void*)(p)

// ---------------------------------------------------------------------------
// prep: blocks [0,256): KV-GEMM 128l x 64d from RAW fp32 (verified);
//       blocks [256,512): wq fp32 -> wqb bf16 flat convert.
// ---------------------------------------------------------------------------
__global__ __launch_bounds__(256) void prep_kernel(
    const float* __restrict__ token, const float* __restrict__ wq,
    const float* __restrict__ wk, const float* __restrict__ wv,
    const float* __restrict__ bk, const float* __restrict__ bv,
    u16* __restrict__ wqb, u16* __restrict__ Kout, u16* __restrict__ Vt)
{
    __shared__ __align__(16) unsigned char smem[32768];
    const int t = threadIdx.x;

    if (blockIdx.x < 256) {
        // ---------------- KV path (verified) ----------------
        const int kvid = blockIdx.x;
        const int xcd = kvid & 7, j = kvid >> 3;
        const int m0 = (xcd * 4 + (j & 3)) * 128;
        const int n0 = (j >> 2) * 64;
        const int lane = t & 63, wid = t >> 6;
        const int i16 = lane & 15, g = lane >> 4;
        const int wm = wid >> 1, wn = wid & 1;
        const int r8 = t >> 3, c8 = t & 7;
        u16* Tok = (u16*)smem;
        u16* Bk  = (u16*)(smem + 16384);
        u16* Bv  = (u16*)(smem + 24576);
        u16 (*LTo)[72] = (u16(*)[72])smem;

        f32x4 ak[4][2], av[4][2];
        #pragma unroll
        for (int mt = 0; mt < 4; ++mt)
            #pragma unroll
            for (int nt = 0; nt < 2; ++nt) {
                ak[mt][nt] = (f32x4){0.f, 0.f, 0.f, 0.f};
                av[mt][nt] = (f32x4){0.f, 0.f, 0.f, 0.f};
            }

        for (int c0 = 0; c0 < C_; c0 += 64) {
            __syncthreads();
            #pragma unroll
            for (int p = 0; p < 4; ++p) {
                const int m = p * 32 + r8;
                cvt8(&token[(size_t)(m0 + m) * C_ + c0 + c8 * 8],
                     &Tok[m * 64 + ((c8 ^ (m & 7)) << 3)]);
            }
            #pragma unroll
            for (int p = 0; p < 2; ++p) {
                const int m = p * 32 + r8;
                const int sw = m * 64 + ((c8 ^ (m & 7)) << 3);
                cvt8(&wk[(size_t)(n0 + m) * C_ + c0 + c8 * 8], &Bk[sw]);
                cvt8(&wv[(size_t)(n0 + m) * C_ + c0 + c8 * 8], &Bv[sw]);
            }
            __syncthreads();
            #pragma unroll
            for (int ks = 0; ks < 2; ++ks) {
                short8_t a[4], bbk[2], bbv[2];
                #pragma unroll
                for (int mt = 0; mt < 4; ++mt) {
                    const int m = wm * 64 + mt * 16 + i16;
                    a[mt] = *(const short8_t*)&Tok[m * 64 + ((((ks << 2) | g) ^ (m & 7)) << 3)];
                }
                #pragma unroll
                for (int nt = 0; nt < 2; ++nt) {
                    const int d = wn * 32 + nt * 16 + i16;
                    const int sw = d * 64 + ((((ks << 2) | g) ^ (d & 7)) << 3);
                    bbk[nt] = *(const short8_t*)&Bk[sw];
                    bbv[nt] = *(const short8_t*)&Bv[sw];
                }
                #pragma unroll
                for (int mt = 0; mt < 4; ++mt)
                    #pragma unroll
                    for (int nt = 0; nt < 2; ++nt) {
                        ak[mt][nt] = __builtin_amdgcn_mfma_f32_16x16x32_bf16(
                            a[mt], bbk[nt], ak[mt][nt], 0, 0, 0);
                        av[mt][nt] = __builtin_amdgcn_mfma_f32_16x16x32_bf16(
                            a[mt], bbv[nt], av[mt][nt], 0, 0, 0);
                    }
            }
        }
        const int nb = m0 >> 8, l0 = m0 & 255;
        const size_t vtbase = (size_t)nb * C_ * L_;
        #pragma unroll
        for (int nt = 0; nt < 2; ++nt) {
            const int d = n0 + wn * 32 + nt * 16 + i16;
            const float bb = bv[d];
            #pragma unroll
            for (int mt = 0; mt < 4; ++mt) {
                ushort4 w;
                w.x = f2bs(av[mt][nt][0] + bb);
                w.y = f2bs(av[mt][nt][1] + bb);
                w.z = f2bs(av[mt][nt][2] + bb);
                w.w = f2bs(av[mt][nt][3] + bb);
                const int l = l0 + wm * 64 + mt * 16 + g * 4;
                *(ushort4*)&Vt[vtbase + (size_t)d * L_ + l] = w;
            }
        }
        __syncthreads();
        #pragma unroll
        for (int nt = 0; nt < 2; ++nt) {
            const int col = wn * 32 + nt * 16 + i16;
            const float bb = bk[n0 + col];
            #pragma unroll
            for (int mt = 0; mt < 4; ++mt)
                #pragma unroll
                for (int r = 0; r < 4; ++r)
                    LTo[wm * 64 + mt * 16 + g * 4 + r][col] = f2bs(ak[mt][nt][r] + bb);
        }
        __syncthreads();
        #pragma unroll
        for (int rep = 0; rep < 4; ++rep) {
            const int m = (t >> 3) + rep * 32;
            const int cs2 = (t & 7) * 8;
            *(short8_t*)&Kout[(size_t)(m0 + m) * C_ + n0 + cs2] = *(short8_t*)&LTo[m][cs2];
        }
    } else {
        // ---------------- wq flat convert (65536 float4) ----------------
        const int idx = (blockIdx.x - 256) * 256 + t;
        float4 v = ((const float4*)wq)[idx];
        ushort4 w;
        w.x = f2bs(v.x); w.y = f2bs(v.y); w.z = f2bs(v.z); w.w = f2bs(v.w);
        ((ushort4*)wqb)[idx] = w;
    }
}

// ---------------------------------------------------------------------------
// qproj: Q[pos][d] = sum_c feature[n][c][pos]*wq[d][c] + bq[d], computed
// per (pos-tile 64 x ALL 512 d) block. 256 blocks x 512 thr (8 waves).
// Feature read ONCE in native layout (256B coalesced rows), transposed into
// a padded LDS tile [64pos][72c] via ds_write_b16 (2-way banks); wq slab
// [512d][64c] via global_load_lds (granule-swizzled). Both double-buffered
// (LDS 146KB), ONE barrier per K-step -> staging covered by 32 MFMA/wave.
// Epilogue: direct ushort4 stores (D col=pos, rows=d), bias added here.
// ---------------------------------------------------------------------------
__global__ __launch_bounds__(512) void qproj_kernel(
    const float* __restrict__ feature, const u16* __restrict__ wqb,
    const float* __restrict__ bq, u16* __restrict__ Qout)
{
    __shared__ __align__(16) unsigned char smem[149504];
    // [0,64K) wq buf0 | [64K,128K) wq buf1 | [128K,+9216) f0 | [+9216,+9216) f1
    const u32 FB = 131072;

    const int t = threadIdx.x;
    const int wv = t >> 6, lane = t & 63;
    const int i16 = lane & 15, g = lane >> 4;
    const int pt = blockIdx.x;
    const int n = pt >> 4, pos0 = (pt & 15) * 64;
    const int fr = t >> 3;          // feature row c within step (0..63)
    const int fp8 = (t & 7) * 8;    // pos start (0..56)

    f32x4 acc[4][4];
    #pragma unroll
    for (int mt = 0; mt < 4; ++mt)
        #pragma unroll
        for (int nt = 0; nt < 4; ++nt)
            acc[mt][nt] = (f32x4){0.f, 0.f, 0.f, 0.f};

    #define QP_STAGE(buf, cs) { \
        _Pragma("unroll") \
        for (int p = 0; p < 8; ++p) { \
            const int gi = p * 512 + t; \
            const int row = gi >> 3, g8 = gi & 7; \
            __builtin_amdgcn_global_load_lds( \
                AS1(wqb + (size_t)row * C_ + (cs) * 64 + ((g8 ^ (row & 7)) << 3)), \
                AS3(smem + (buf) * 65536 + gi * 16), 16, 0, 0); } \
        { \
            float f8[8]; \
            const float* src = &feature[((size_t)n * C_ + (cs) * 64 + fr) * HW_ + pos0 + fp8]; \
            *(float4*)&f8[0] = *(const float4*)&src[0]; \
            *(float4*)&f8[4] = *(const float4*)&src[4]; \
            u16* fb = (u16*)(smem + FB + (buf) * 9216); \
            _Pragma("unroll") \
            for (int jj = 0; jj < 8; ++jj) \
                fb[(fp8 + jj) * 72 + fr] = f2bs(f8[jj]); \
        } }

    #define QP_COMPUTE(buf) { \
        const u16* wqs = (const u16*)(smem + (buf) * 65536); \
        const u16* fts = (const u16*)(smem + FB + (buf) * 9216); \
        _Pragma("unroll") \
        for (int ks = 0; ks < 2; ++ks) { \
            short8_t a[4], b[4]; \
            _Pragma("unroll") \
            for (int mt = 0; mt < 4; ++mt) { \
                const int d = wv * 64 + mt * 16 + i16; \
                a[mt] = *(const short8_t*)&wqs[d * 64 + ((((ks << 2) | g) ^ (d & 7)) << 3)]; } \
            _Pragma("unroll") \
            for (int nt = 0; nt < 4; ++nt) { \
                const int pos = nt * 16 + i16; \
                b[nt] = *(const short8_t*)&fts[pos * 72 + ks * 32 + g * 8]; } \
            _Pragma("unroll") \
            for (int mt = 0; mt < 4; ++mt) \
                _Pragma("unroll") \
                for (int nt = 0; nt < 4; ++nt) \
                    acc[mt][nt] = __builtin_amdgcn_mfma_f32_16x16x32_bf16( \
                        a[mt], b[nt], acc[mt][nt], 0, 0, 0); } }

    QP_STAGE(0, 0);
    __syncthreads();
    #pragma unroll
    for (int cs = 0; cs < 8; ++cs) {
        const int cur = cs & 1;
        if (cs < 7) QP_STAGE(cur ^ 1, cs + 1);
        QP_COMPUTE(cur);
        __syncthreads();
    }

    // epilogue: lane holds 4 consecutive d for column pos; bias added here
    #pragma unroll
    for (int mt = 0; mt < 4; ++mt) {
        const int dbase = wv * 64 + mt * 16 + g * 4;
        float4 b4 = *(const float4*)&bq[dbase];
        #pragma unroll
        for (int nt = 0; nt < 4; ++nt) {
            const int pos = nt * 16 + i16;
            ushort4 w;
            w.x = f2bs(acc[mt][nt][0] + b4.x);
            w.y = f2bs(acc[mt][nt][1] + b4.y);
            w.z = f2bs(acc[mt][nt][2] + b4.z);
            w.w = f2bs(acc[mt][nt][3] + b4.w);
            *(ushort4*)&Qout[(size_t)(n * HW_ + pos0 + pos) * C_ + dbase] = w;
        }
    }
}

// ---------------------------------------------------------------------------
// attn v2.1 (verified, byte-identical).
// ---------------------------------------------------------------------------
__global__ __launch_bounds__(256) void attn_kernel(
    const u16* __restrict__ Qws, const u16* __restrict__ Kws,
    const u16* __restrict__ Vws, const float* __restrict__ feature,
    float* __restrict__ out)
{
    __shared__ __align__(16) unsigned char smem[32768];

    const int t = threadIdx.x;
    const int wid = t >> 6, lane = t & 63;
    const int i16 = lane & 15, g = lane >> 4;
    const int pt = blockIdx.x, h = blockIdx.y, n = blockIdx.z;
    const int pos0 = pt * 64;
    const size_t qbase = ((size_t)n * HW_ + pos0) * C_ + h * DH_;
    const size_t kbase = ((size_t)n * L_) * C_ + h * DH_;
    const size_t vbase = (size_t)n * C_ * L_ + (size_t)h * DH_ * L_;

    const int q = wid * 16 + i16;

    short8_t bq = *(const short8_t*)&Qws[qbase + (size_t)q * C_ + g * 8];

    #pragma unroll
    for (int p = 0; p < 4; ++p) {
        const int kg = (lane & 3) ^ ((lane >> 3) & 3);
        const int kr = wid * 64 + p * 16 + (lane >> 2);
        const u16* ksrc = Kws + kbase + (size_t)kr * C_ + kg * 8;
        __builtin_amdgcn_global_load_lds(AS1(ksrc),
            AS3(smem + wid * 4096 + p * 1024), 16, 0, 0);
        const int vd = wid * 8 + p * 2 + (lane >> 5);
        const u16* vsrc = Vws + vbase + (size_t)vd * L_ + ((lane & 31) ^ (vd & 7)) * 8;
        __builtin_amdgcn_global_load_lds(AS1(vsrc),
            AS3(smem + 16384 + wid * 4096 + p * 1024), 16, 0, 0);
    }
    __syncthreads();

    const int kgr = g ^ ((i16 >> 1) & 3);
    f32x4 s[16];
    #pragma unroll
    for (int nf = 0; nf < 16; ++nf) {
        short8_t a = *(const short8_t*)(smem + (nf * 16 + i16) * 64 + kgr * 16);
        f32x4 z = {0.f, 0.f, 0.f, 0.f};
        s[nf] = __builtin_amdgcn_mfma_f32_16x16x32_bf16(a, bq, z, 0, 0, 0);
    }

    float mm[16], sm[16];
    #pragma unroll
    for (int nf = 0; nf < 16; ++nf)
        mm[nf] = fmaxf(fmaxf(s[nf][0], s[nf][1]), fmaxf(s[nf][2], s[nf][3]));
    #pragma unroll
    for (int st = 8; st >= 1; st >>= 1)
        #pragma unroll
        for (int i = 0; i < 8; ++i)
            if (i < st) mm[i] = fmaxf(mm[i], mm[i + st]);
    float m = mm[0];
    m = fmaxf(m, __shfl_xor(m, 16));
    m = fmaxf(m, __shfl_xor(m, 32));

    const float K2 = 0.25506288f;  // log2(e) / sqrt(32)
    #pragma unroll
    for (int nf = 0; nf < 16; ++nf) {
        #pragma unroll
        for (int r = 0; r < 4; ++r) s[nf][r] = exp2f((s[nf][r] - m) * K2);
        sm[nf] = (s[nf][0] + s[nf][1]) + (s[nf][2] + s[nf][3]);
    }
    #pragma unroll
    for (int st = 8; st >= 1; st >>= 1)
        #pragma unroll
        for (int i = 0; i < 8; ++i)
            if (i < st) sm[i] += sm[i + st];
    float ssum = sm[0];
    ssum += __shfl_xor(ssum, 16);
    ssum += __shfl_xor(ssum, 32);
    const float pinv = 1.0f / ssum;

    __syncthreads();  // K dead -> P may alias

    f32x4 o0 = {0.f, 0.f, 0.f, 0.f}, o1 = {0.f, 0.f, 0.f, 0.f};
    const int e7 = i16 & 7;

    #pragma unroll
    for (int hb = 0; hb < 2; ++hb) {
        #pragma unroll
        for (int nfp = 0; nfp < 8; ++nfp) {
            const int nf = hb * 8 + nfp;
            #pragma unroll
            for (int w = 0; w < 2; ++w) {
                u32 pw = cvt_pk_bf16(s[nf][2 * w] * pinv, s[nf][2 * w + 1] * pinv);
                const int gran = (nfp * 2 + (g >> 1)) ^ e7;
                *(u32*)(smem + q * 256 + gran * 16 + ((g & 1) * 2 + w) * 4) = pw;
            }
        }
        __syncthreads();
        #pragma unroll
        for (int ks = 0; ks < 4; ++ks) {
            short8_t pb = *(const short8_t*)(smem + q * 256 + (((ks * 4 + g) ^ e7) * 16));
            const int vg = (((hb * 4 + ks) * 4 + g) ^ e7) * 16;
            short8_t va0 = *(const short8_t*)(smem + 16384 + i16 * 512 + vg);
            short8_t va1 = *(const short8_t*)(smem + 16384 + (16 + i16) * 512 + vg);
            o0 = __builtin_amdgcn_mfma_f32_16x16x32_bf16(va0, pb, o0, 0, 0, 0);
            o1 = __builtin_amdgcn_mfma_f32_16x16x32_bf16(va1, pb, o1, 0, 0, 0);
        }
        if (hb == 0) __syncthreads();
    }

    const size_t obase = ((size_t)n * C_ + h * DH_) * HW_ + pos0 + q;
    #pragma unroll
    for (int r = 0; r < 4; ++r) {
        const size_t oa = obase + (size_t)(g * 4 + r) * HW_;
        out[oa] = feature[oa] + o0[r];
        const size_t ob = obase + (size_t)(16 + g * 4 + r) * HW_;
        out[ob] = feature[ob] + o1[r];
    }
}

extern "C" void kernel_launch(void* const* d_in, const int* in_sizes, int n_in,
                              void* d_out, int out_size, void* d_ws, size_t ws_size,
                              hipStream_t stream)
{
    const float* feature = (const float*)d_in[0];
    const float* token   = (const float*)d_in[1];
    const float* wq      = (const float*)d_in[2];
    const float* bq      = (const float*)d_in[3];
    const float* wk      = (const float*)d_in[4];
    const float* bk      = (const float*)d_in[5];
    const float* wv      = (const float*)d_in[6];
    const float* bv      = (const float*)d_in[7];
    float* out = (float*)d_out;

    // d_ws: Q [16384][512] bf16 (16 MiB) | K (4 MiB) | Vt [n][d][l] (4 MiB)
    u16* Qws = (u16*)d_ws;
    u16* Kws = Qws + (size_t)N_ * HW_ * C_;
    u16* Vws = Kws + (size_t)N_ * L_ * C_;

    // d_out scratch (consumed by qproj before attn writes out): wqb 0.5 MiB
    u16* wqb = (u16*)((char*)d_out + (21u << 20));

    prep_kernel<<<dim3(512), 256, 0, stream>>>(token, wq, wk, wv, bk, bv,
                                               wqb, Kws, Vws);
    qproj_kernel<<<dim3(256), 512, 0, stream>>>(feature, wqb, bq, Qws);
    attn_kernel<<<dim3(16, 16, 16), 256, 0, stream>>>(Qws, Kws, Vws, feature, out);
}

// Round 19
// 70.883 us; speedup vs baseline: 1.1136x; 1.1136x over previous
//
#include <hip/hip_runtime.h>
#include <hip/hip_bf16.h>

#define N_ 16
#define L_ 256
#define C_ 512
#define HW_ 1024
#define HEADS_ 16
#define DH_ 32

typedef unsigned short u16;
typedef unsigned int u32;
typedef __attribute__((ext_vector_type(8))) short short8_t;
typedef __attribute__((ext_vector_type(4))) float f32x4;

__device__ __forceinline__ u16 f2bs(float f) {
    union { float f; u32 i; } x; x.f = f;
    u32 r = x.i + 0x7fffu + ((x.i >> 16) & 1u);
    return (u16)(r >> 16);
}
__device__ __forceinline__ u32 cvt_pk_bf16(float lo, float hi) {
    u32 r;
    asm("v_cvt_pk_bf16_f32 %0, %1, %2" : "=v"(r) : "v"(lo), "v"(hi));
    return r;
}
#define AS1(p) (const __attribute__((address_space(1))) void*)(p)
#define AS3(p) (__attribute__((address_space(3))) void*)(p)

// ---------------------------------------------------------------------------
// prep: blocks [0,2816): flat fp32->bf16 (token, wq, wk, wv).
//       blocks [2816,4864): feature [n][c][pos] f32 -> Ftb [(n*HW+pos)][c]
//       bf16 via 64x64 LDS transpose tiles (pure streaming BW).
// ---------------------------------------------------------------------------
__global__ __launch_bounds__(256) void prep_kernel(
    const float* __restrict__ token, const float* __restrict__ wq,
    const float* __restrict__ wk, const float* __restrict__ wv,
    const float* __restrict__ feature,
    u16* __restrict__ tokb, u16* __restrict__ wqb,
    u16* __restrict__ wkb, u16* __restrict__ wvb,
    u16* __restrict__ Ftb)
{
    __shared__ float LT[64][67];
    const int t = threadIdx.x;

    if (blockIdx.x < 2816) {
        const int idx = blockIdx.x * 256 + t;
        const float* s; u16* d; int off;
        if (idx < 524288)            { s = token; d = tokb; off = idx; }
        else if (idx < 524288+65536) { s = wq; d = wqb; off = idx - 524288; }
        else if (idx < 524288+131072){ s = wk; d = wkb; off = idx - 524288 - 65536; }
        else                         { s = wv; d = wvb; off = idx - 524288 - 131072; }
        float4 v = ((const float4*)s)[off];
        ushort4 w;
        w.x = f2bs(v.x); w.y = f2bs(v.y); w.z = f2bs(v.z); w.w = f2bs(v.w);
        ((ushort4*)d)[off] = w;
    } else {
        const int tidx = blockIdx.x - 2816;
        const int pb = tidx & 15, cb = (tidx >> 4) & 7, n = tidx >> 7;
        const int c0 = cb * 64, pos0 = pb * 64;

        #pragma unroll
        for (int r = 0; r < 4; ++r) {
            const int c = r * 16 + (t >> 4);
            const int p = (t & 15) * 4;
            float4 v = *(const float4*)&feature[
                ((size_t)n * C_ + c0 + c) * HW_ + pos0 + p];
            LT[c][p] = v.x; LT[c][p+1] = v.y; LT[c][p+2] = v.z; LT[c][p+3] = v.w;
        }
        __syncthreads();
        #pragma unroll
        for (int rep = 0; rep < 2; ++rep) {
            const int pos = (t >> 3) + rep * 32;
            const int c = (t & 7) * 8;
            u16 tmp[8];
            #pragma unroll
            for (int j = 0; j < 8; ++j) tmp[j] = f2bs(LT[c + j][pos]);
            *(short8_t*)&Ftb[(size_t)(n * HW_ + pos0 + pos) * C_ + c0 + c] =
                *(short8_t*)tmp;
        }
    }
}

// ---------------------------------------------------------------------------
// gemm_kernel: one dispatch, both paths pure-bf16 KV-style (global_load_lds
// staging, plain ds_read_b128 frags, no inline asm, no cvt in loop).
//  blocks [0,256): KV — 128l x 64d token GEMM -> K row-major + V^T (verified).
//  blocks [256,1280): Q — 128pos x 64d Ftb GEMM -> Qws row-major (LDS bounce).
// ---------------------------------------------------------------------------
__global__ __launch_bounds__(256) void gemm_kernel(
    const u16* __restrict__ Ftb, const u16* __restrict__ tokb,
    const u16* __restrict__ wqb, const u16* __restrict__ wkb,
    const u16* __restrict__ wvb,
    const float* __restrict__ bq, const float* __restrict__ bk,
    const float* __restrict__ bv,
    u16* __restrict__ Qout, u16* __restrict__ Kout, u16* __restrict__ Vt)
{
    __shared__ __align__(16) unsigned char smem[32768];

    const int t = threadIdx.x;
    const int lane = t & 63, wid = t >> 6;
    const int i16 = lane & 15, g = lane >> 4;
    const int wm = wid >> 1, wn = wid & 1;
    const int r8 = t >> 3, gr = t & 7;

    if (blockIdx.x < 256) {
        // ================= KV path (verified, unchanged) =================
        const int xcd = blockIdx.x & 7, j = blockIdx.x >> 3;
        const int m0 = (xcd * 4 + (j & 3)) * 128;
        const int n0 = (j >> 2) * 64;
        u16* Tok = (u16*)smem;
        u16* Bk  = (u16*)(smem + 16384);
        u16* Bv  = (u16*)(smem + 24576);
        u16 (*LTo)[72] = (u16(*)[72])smem;

        f32x4 ak[4][2], av[4][2];
        #pragma unroll
        for (int mt = 0; mt < 4; ++mt)
            #pragma unroll
            for (int nt = 0; nt < 2; ++nt) {
                ak[mt][nt] = (f32x4){0.f, 0.f, 0.f, 0.f};
                av[mt][nt] = (f32x4){0.f, 0.f, 0.f, 0.f};
            }

        for (int c0 = 0; c0 < C_; c0 += 64) {
            __syncthreads();
            #pragma unroll
            for (int p = 0; p < 4; ++p) {
                const int row = p * 32 + r8;
                __builtin_amdgcn_global_load_lds(
                    AS1(tokb + (size_t)(m0 + row) * C_ + c0 + ((gr ^ (row & 7)) << 3)),
                    AS3(smem + (p * 32 + wid * 8) * 128), 16, 0, 0);
            }
            #pragma unroll
            for (int p = 0; p < 2; ++p) {
                const int row = p * 32 + r8;
                const int gs = (gr ^ (row & 7)) << 3;
                __builtin_amdgcn_global_load_lds(
                    AS1(wkb + (size_t)(n0 + row) * C_ + c0 + gs),
                    AS3(smem + 16384 + (p * 32 + wid * 8) * 128), 16, 0, 0);
                __builtin_amdgcn_global_load_lds(
                    AS1(wvb + (size_t)(n0 + row) * C_ + c0 + gs),
                    AS3(smem + 24576 + (p * 32 + wid * 8) * 128), 16, 0, 0);
            }
            __syncthreads();
            #pragma unroll
            for (int ks = 0; ks < 2; ++ks) {
                short8_t a[4], bbk[2], bbv[2];
                #pragma unroll
                for (int mt = 0; mt < 4; ++mt) {
                    const int m = wm * 64 + mt * 16 + i16;
                    a[mt] = *(const short8_t*)&Tok[m * 64 + ((((ks << 2) | g) ^ (m & 7)) << 3)];
                }
                #pragma unroll
                for (int nt = 0; nt < 2; ++nt) {
                    const int d = wn * 32 + nt * 16 + i16;
                    const int sw = d * 64 + ((((ks << 2) | g) ^ (d & 7)) << 3);
                    bbk[nt] = *(const short8_t*)&Bk[sw];
                    bbv[nt] = *(const short8_t*)&Bv[sw];
                }
                #pragma unroll
                for (int mt = 0; mt < 4; ++mt)
                    #pragma unroll
                    for (int nt = 0; nt < 2; ++nt) {
                        ak[mt][nt] = __builtin_amdgcn_mfma_f32_16x16x32_bf16(
                            a[mt], bbk[nt], ak[mt][nt], 0, 0, 0);
                        av[mt][nt] = __builtin_amdgcn_mfma_f32_16x16x32_bf16(
                            a[mt], bbv[nt], av[mt][nt], 0, 0, 0);
                    }
            }
        }
        const int nb = m0 >> 8, l0 = m0 & 255;
        const size_t vtbase = (size_t)nb * C_ * L_;
        #pragma unroll
        for (int nt = 0; nt < 2; ++nt) {
            const int d = n0 + wn * 32 + nt * 16 + i16;
            const float bb = bv[d];
            #pragma unroll
            for (int mt = 0; mt < 4; ++mt) {
                ushort4 w;
                w.x = f2bs(av[mt][nt][0] + bb);
                w.y = f2bs(av[mt][nt][1] + bb);
                w.z = f2bs(av[mt][nt][2] + bb);
                w.w = f2bs(av[mt][nt][3] + bb);
                const int l = l0 + wm * 64 + mt * 16 + g * 4;
                *(ushort4*)&Vt[vtbase + (size_t)d * L_ + l] = w;
            }
        }
        __syncthreads();
        #pragma unroll
        for (int nt = 0; nt < 2; ++nt) {
            const int col = wn * 32 + nt * 16 + i16;
            const float bb = bk[n0 + col];
            #pragma unroll
            for (int mt = 0; mt < 4; ++mt)
                #pragma unroll
                for (int r = 0; r < 4; ++r)
                    LTo[wm * 64 + mt * 16 + g * 4 + r][col] = f2bs(ak[mt][nt][r] + bb);
        }
        __syncthreads();
        #pragma unroll
        for (int rep = 0; rep < 4; ++rep) {
            const int m = (t >> 3) + rep * 32;
            const int cs = (t & 7) * 8;
            *(short8_t*)&Kout[(size_t)(m0 + m) * C_ + n0 + cs] = *(short8_t*)&LTo[m][cs];
        }
    } else {
        // ============ Q path: 128pos x 64d, KV-style, single output ==========
        const int qid = blockIdx.x - 256;
        const int xcd = qid & 7, j = qid >> 3;
        const int m0 = (xcd * 16 + (j & 15)) * 128;   // 128 m-tiles of 128 pos
        const int n0 = (j >> 4) * 64;                 // 8 d-tiles
        u16* Ft = (u16*)smem;                         // [128][64] gran-swz 16KB
        u16* Bq = (u16*)(smem + 16384);               // [64][64] 8KB
        u16 (*LTo)[72] = (u16(*)[72])smem;            // bounce 18.4KB (aliases)

        f32x4 aq[4][2];
        #pragma unroll
        for (int mt = 0; mt < 4; ++mt)
            #pragma unroll
            for (int nt = 0; nt < 2; ++nt)
                aq[mt][nt] = (f32x4){0.f, 0.f, 0.f, 0.f};

        for (int c0 = 0; c0 < C_; c0 += 64) {
            __syncthreads();
            #pragma unroll
            for (int p = 0; p < 4; ++p) {
                const int row = p * 32 + r8;
                __builtin_amdgcn_global_load_lds(
                    AS1(Ftb + (size_t)(m0 + row) * C_ + c0 + ((gr ^ (row & 7)) << 3)),
                    AS3(smem + (p * 32 + wid * 8) * 128), 16, 0, 0);
            }
            #pragma unroll
            for (int p = 0; p < 2; ++p) {
                const int row = p * 32 + r8;
                __builtin_amdgcn_global_load_lds(
                    AS1(wqb + (size_t)(n0 + row) * C_ + c0 + ((gr ^ (row & 7)) << 3)),
                    AS3(smem + 16384 + (p * 32 + wid * 8) * 128), 16, 0, 0);
            }
            __syncthreads();
            #pragma unroll
            for (int ks = 0; ks < 2; ++ks) {
                short8_t a[4], b[2];
                #pragma unroll
                for (int mt = 0; mt < 4; ++mt) {
                    const int m = wm * 64 + mt * 16 + i16;
                    a[mt] = *(const short8_t*)&Ft[m * 64 + ((((ks << 2) | g) ^ (m & 7)) << 3)];
                }
                #pragma unroll
                for (int nt = 0; nt < 2; ++nt) {
                    const int d = wn * 32 + nt * 16 + i16;
                    b[nt] = *(const short8_t*)&Bq[d * 64 + ((((ks << 2) | g) ^ (d & 7)) << 3)];
                }
                #pragma unroll
                for (int mt = 0; mt < 4; ++mt)
                    #pragma unroll
                    for (int nt = 0; nt < 2; ++nt)
                        aq[mt][nt] = __builtin_amdgcn_mfma_f32_16x16x32_bf16(
                            a[mt], b[nt], aq[mt][nt], 0, 0, 0);
            }
        }
        __syncthreads();
        #pragma unroll
        for (int nt = 0; nt < 2; ++nt) {
            const int col = wn * 32 + nt * 16 + i16;
            const float bb = bq[n0 + col];
            #pragma unroll
            for (int mt = 0; mt < 4; ++mt)
                #pragma unroll
                for (int r = 0; r < 4; ++r)
                    LTo[wm * 64 + mt * 16 + g * 4 + r][col] = f2bs(aq[mt][nt][r] + bb);
        }
        __syncthreads();
        #pragma unroll
        for (int rep = 0; rep < 4; ++rep) {
            const int m = (t >> 3) + rep * 32;
            const int cs = (t & 7) * 8;
            *(short8_t*)&Qout[(size_t)(m0 + m) * C_ + n0 + cs] = *(short8_t*)&LTo[m][cs];
        }
    }
}

// ---------------------------------------------------------------------------
// attn v2.1 (verified, byte-identical).
// ---------------------------------------------------------------------------
__global__ __launch_bounds__(256) void attn_kernel(
    const u16* __restrict__ Qws, const u16* __restrict__ Kws,
    const u16* __restrict__ Vws, const float* __restrict__ feature,
    float* __restrict__ out)
{
    __shared__ __align__(16) unsigned char smem[32768];

    const int t = threadIdx.x;
    const int wid = t >> 6, lane = t & 63;
    const int i16 = lane & 15, g = lane >> 4;
    const int pt = blockIdx.x, h = blockIdx.y, n = blockIdx.z;
    const int pos0 = pt * 64;
    const size_t qbase = ((size_t)n * HW_ + pos0) * C_ + h * DH_;
    const size_t kbase = ((size_t)n * L_) * C_ + h * DH_;
    const size_t vbase = (size_t)n * C_ * L_ + (size_t)h * DH_ * L_;

    const int q = wid * 16 + i16;

    short8_t bq = *(const short8_t*)&Qws[qbase + (size_t)q * C_ + g * 8];

    #pragma unroll
    for (int p = 0; p < 4; ++p) {
        const int kg = (lane & 3) ^ ((lane >> 3) & 3);
        const int kr = wid * 64 + p * 16 + (lane >> 2);
        const u16* ksrc = Kws + kbase + (size_t)kr * C_ + kg * 8;
        __builtin_amdgcn_global_load_lds(AS1(ksrc),
            AS3(smem + wid * 4096 + p * 1024), 16, 0, 0);
        const int vd = wid * 8 + p * 2 + (lane >> 5);
        const u16* vsrc = Vws + vbase + (size_t)vd * L_ + ((lane & 31) ^ (vd & 7)) * 8;
        __builtin_amdgcn_global_load_lds(AS1(vsrc),
            AS3(smem + 16384 + wid * 4096 + p * 1024), 16, 0, 0);
    }
    __syncthreads();

    const int kgr = g ^ ((i16 >> 1) & 3);
    f32x4 s[16];
    #pragma unroll
    for (int nf = 0; nf < 16; ++nf) {
        short8_t a = *(const short8_t*)(smem + (nf * 16 + i16) * 64 + kgr * 16);
        f32x4 z = {0.f, 0.f, 0.f, 0.f};
        s[nf] = __builtin_amdgcn_mfma_f32_16x16x32_bf16(a, bq, z, 0, 0, 0);
    }

    float mm[16], sm[16];
    #pragma unroll
    for (int nf = 0; nf < 16; ++nf)
        mm[nf] = fmaxf(fmaxf(s[nf][0], s[nf][1]), fmaxf(s[nf][2], s[nf][3]));
    #pragma unroll
    for (int st = 8; st >= 1; st >>= 1)
        #pragma unroll
        for (int i = 0; i < 8; ++i)
            if (i < st) mm[i] = fmaxf(mm[i], mm[i + st]);
    float m = mm[0];
    m = fmaxf(m, __shfl_xor(m, 16));
    m = fmaxf(m, __shfl_xor(m, 32));

    const float K2 = 0.25506288f;  // log2(e) / sqrt(32)
    #pragma unroll
    for (int nf = 0; nf < 16; ++nf) {
        #pragma unroll
        for (int r = 0; r < 4; ++r) s[nf][r] = exp2f((s[nf][r] - m) * K2);
        sm[nf] = (s[nf][0] + s[nf][1]) + (s[nf][2] + s[nf][3]);
    }
    #pragma unroll
    for (int st = 8; st >= 1; st >>= 1)
        #pragma unroll
        for (int i = 0; i < 8; ++i)
            if (i < st) sm[i] += sm[i + st];
    float ssum = sm[0];
    ssum += __shfl_xor(ssum, 16);
    ssum += __shfl_xor(ssum, 32);
    const float pinv = 1.0f / ssum;

    __syncthreads();  // K dead -> P may alias

    f32x4 o0 = {0.f, 0.f, 0.f, 0.f}, o1 = {0.f, 0.f, 0.f, 0.f};
    const int e7 = i16 & 7;

    #pragma unroll
    for (int hb = 0; hb < 2; ++hb) {
        #pragma unroll
        for (int nfp = 0; nfp < 8; ++nfp) {
            const int nf = hb * 8 + nfp;
            #pragma unroll
            for (int w = 0; w < 2; ++w) {
                u32 pw = cvt_pk_bf16(s[nf][2 * w] * pinv, s[nf][2 * w + 1] * pinv);
                const int gran = (nfp * 2 + (g >> 1)) ^ e7;
                *(u32*)(smem + q * 256 + gran * 16 + ((g & 1) * 2 + w) * 4) = pw;
            }
        }
        __syncthreads();
        #pragma unroll
        for (int ks = 0; ks < 4; ++ks) {
            short8_t pb = *(const short8_t*)(smem + q * 256 + (((ks * 4 + g) ^ e7) * 16));
            const int vg = (((hb * 4 + ks) * 4 + g) ^ e7) * 16;
            short8_t va0 = *(const short8_t*)(smem + 16384 + i16 * 512 + vg);
            short8_t va1 = *(const short8_t*)(smem + 16384 + (16 + i16) * 512 + vg);
            o0 = __builtin_amdgcn_mfma_f32_16x16x32_bf16(va0, pb, o0, 0, 0, 0);
            o1 = __builtin_amdgcn_mfma_f32_16x16x32_bf16(va1, pb, o1, 0, 0, 0);
        }
        if (hb == 0) __syncthreads();
    }

    const size_t obase = ((size_t)n * C_ + h * DH_) * HW_ + pos0 + q;
    #pragma unroll
    for (int r = 0; r < 4; ++r) {
        const size_t oa = obase + (size_t)(g * 4 + r) * HW_;
        out[oa] = feature[oa] + o0[r];
        const size_t ob = obase + (size_t)(16 + g * 4 + r) * HW_;
        out[ob] = feature[ob] + o1[r];
    }
}

extern "C" void kernel_launch(void* const* d_in, const int* in_sizes, int n_in,
                              void* d_out, int out_size, void* d_ws, size_t ws_size,
                              hipStream_t stream)
{
    const float* feature = (const float*)d_in[0];
    const float* token   = (const float*)d_in[1];
    const float* wq      = (const float*)d_in[2];
    const float* bq      = (const float*)d_in[3];
    const float* wk      = (const float*)d_in[4];
    const float* bk      = (const float*)d_in[5];
    const float* wv      = (const float*)d_in[6];
    const float* bv      = (const float*)d_in[7];
    float* out = (float*)d_out;

    // d_ws: Q [16384][512] bf16 (16 MiB) | K (4 MiB) | Vt [n][d][l] (4 MiB)
    u16* Qws = (u16*)d_ws;
    u16* Kws = Qws + (size_t)N_ * HW_ * C_;
    u16* Vws = Kws + (size_t)N_ * L_ * C_;

    // d_out scratch (consumed by gemm before attn writes out):
    //   [0,16M): Ftb bf16 | [16M,20M): token bf16 | [20M,+1M): wk/wv | [21M): wq
    char* ob = (char*)d_out;
    u16* Ftb  = (u16*)ob;
    u16* tokb = (u16*)(ob + (16u << 20));
    u16* wkb  = (u16*)(ob + (20u << 20));
    u16* wvb  = (u16*)(ob + (20u << 20) + 524288);
    u16* wqb  = (u16*)(ob + (21u << 20));

    prep_kernel<<<dim3(4864), 256, 0, stream>>>(token, wq, wk, wv, feature,
                                                tokb, wqb, wkb, wvb, Ftb);
    gemm_kernel<<<dim3(1280), 256, 0, stream>>>(Ftb, tokb, wqb, wkb, wvb,
                                                bq, bk, bv, Qws, Kws, Vws);
    attn_kernel<<<dim3(16, 16, 16), 256, 0, stream>>>(Qws, Kws, Vws, feature, out);
}